// Round 7
// baseline (355.034 us; speedup 1.0000x reference)
//
#include <hip/hip_runtime.h>
#include <hip/hip_bf16.h>

// Problem constants (B=4, T=2048, C=1024, H=16, HD=64)
#define BB 4
#define TT 2048
#define CC 1024
#define HH 16
#define HD 64
#define NX  (BB * TT * CC)     // 8388608
#define NWA (3 * CC * CC)      // 3145728
#define NWP (CC * CC)          // 1048576

typedef _Float16 half8 __attribute__((ext_vector_type(8)));
typedef _Float16 half4 __attribute__((ext_vector_type(4)));
typedef _Float16 half2_t __attribute__((ext_vector_type(2)));
typedef float floatx4 __attribute__((ext_vector_type(4)));

// async global->LDS, 16B per lane (dest = wave-uniform base + lane*16)
__device__ __forceinline__ void async_cp16(const void* g, void* l) {
    __builtin_amdgcn_global_load_lds(
        (const __attribute__((address_space(1))) unsigned int*)g,
        (__attribute__((address_space(3))) unsigned int*)l,
        16, 0, 0);
}

// ---------------------------------------------------------------------------
// fused fp32 -> fp16 conversion of x, W_attn, W_proj (one launch)
// ---------------------------------------------------------------------------
__global__ void cvt_all(const float* __restrict__ x, const float* __restrict__ wa,
                        const float* __restrict__ wp,
                        _Float16* __restrict__ xh, _Float16* __restrict__ wah,
                        _Float16* __restrict__ wph) {
    int i = (blockIdx.x * blockDim.x + threadIdx.x) * 8;
    const float* s; _Float16* d; int j;
    if (i < NX)            { s = x;  d = xh;  j = i; }
    else if (i < NX + NWA) { s = wa; d = wah; j = i - NX; }
    else                   { s = wp; d = wph; j = i - NX - NWA; }
    float4 v0 = *(const float4*)(s + j);
    float4 v1 = *(const float4*)(s + j + 4);
    half8 h;
    h[0] = (_Float16)v0.x; h[1] = (_Float16)v0.y; h[2] = (_Float16)v0.z; h[3] = (_Float16)v0.w;
    h[4] = (_Float16)v1.x; h[5] = (_Float16)v1.y; h[6] = (_Float16)v1.z; h[7] = (_Float16)v1.w;
    *(half8*)(d + j) = h;
}

// ---------------------------------------------------------------------------
// NT GEMM, m97 structure (R4): C[m][n] = sum_k A[m][k]*Bw[n][k] + bias[n]
// 128x128 tile, BK=32, 256 thr (4 waves 2x2), global_load_lds width-16.
// EPI=0: LDS-bounce epilogue (Cs stride 132, fixed R6 overflow) -> coalesced
//        half8 stores of Q(scaled)/K/V fp16 [B*H, T, 64].
// EPI=1: fp32 direct -> c_out[m*N+n] (dword stores, already coalesced)
// ---------------------------------------------------------------------------
template <int EPI>
__global__ __launch_bounds__(256) void hgemm_nt(
    const _Float16* __restrict__ A, const _Float16* __restrict__ Bw,
    const float* __restrict__ bias,
    _Float16* __restrict__ q_out, _Float16* __restrict__ k_out, _Float16* __restrict__ v_out,
    float* __restrict__ c_out,
    int M, int N, int K)
{
    // staging uses Sm[0..8192); EPI=0 epilogue reuses Sm as Cs[128][132]
    __shared__ __attribute__((aligned(16))) _Float16 Sm[EPI == 0 ? 128 * 132 : 8192];
    _Float16* As = Sm;          // 128x32 packed
    _Float16* Bs = Sm + 4096;

    const int tid  = threadIdx.x;
    const int lane = tid & 63;
    const int wave = tid >> 6;
    const int quad = lane >> 4;
    const int lc   = lane & 15;
    const int wr   = wave >> 1, wc = wave & 1;
    const size_t bm = (size_t)blockIdx.y * 128;
    const size_t bn = (size_t)blockIdx.x * 128;

    const int r0 = tid >> 2;        // 0..63
    const int ck = (tid & 3) * 8;   // 0,8,16,24

    const _Float16* Ap0 = A + (bm + r0) * (size_t)K + ck;
    const _Float16* Ap1 = A + (bm + 64 + r0) * (size_t)K + ck;
    const _Float16* Bp0 = Bw + (bn + r0) * (size_t)K + ck;
    const _Float16* Bp1 = Bw + (bn + 64 + r0) * (size_t)K + ck;
    _Float16* lA0 = As + tid * 8;
    _Float16* lA1 = As + 2048 + tid * 8;
    _Float16* lB0 = Bs + tid * 8;
    _Float16* lB1 = Bs + 2048 + tid * 8;

    floatx4 acc[4][4] = {};

    for (int kk = 0; kk < K; kk += 32) {
        __syncthreads();  // previous tile fully consumed
        async_cp16(Ap0 + kk, lA0);
        async_cp16(Ap1 + kk, lA1);
        async_cp16(Bp0 + kk, lB0);
        async_cp16(Bp1 + kk, lB1);
        __syncthreads();  // barrier drains vmcnt -> staging visible

        half8 af[4], bf[4];
#pragma unroll
        for (int mt = 0; mt < 4; mt++) af[mt] = *(const half8*)(As + (wr * 64 + mt * 16 + lc) * 32 + quad * 8);
#pragma unroll
        for (int nt = 0; nt < 4; nt++) bf[nt] = *(const half8*)(Bs + (wc * 64 + nt * 16 + lc) * 32 + quad * 8);
#pragma unroll
        for (int mt = 0; mt < 4; mt++)
#pragma unroll
            for (int nt = 0; nt < 4; nt++)
                acc[mt][nt] = __builtin_amdgcn_mfma_f32_16x16x32_f16(af[mt], bf[nt], acc[mt][nt], 0, 0, 0);
    }

    if (EPI == 0) {
        // ---- LDS-bounce epilogue: acc -> Cs[m_loc][132] -> coalesced stores
        const int seg = (int)(bn >> 10);        // uniform per block (bn % 128 == 0)
        __syncthreads();  // all As/Bs reads done before reusing Sm
#pragma unroll
        for (int mt = 0; mt < 4; mt++) {
            int m_loc = wr * 64 + mt * 16 + quad * 4;
#pragma unroll
            for (int nt = 0; nt < 4; nt++) {
                int n_loc = wc * 64 + nt * 16 + lc;
                float bv = bias[bn + n_loc];
#pragma unroll
                for (int r = 0; r < 4; r++) {
                    float v = acc[mt][nt][r] + bv;
                    if (seg == 0) v *= 0.18033688f;  // 1/sqrt(HD) * log2(e)
                    Sm[(m_loc + r) * 132 + n_loc] = (_Float16)v;
                }
            }
        }
        __syncthreads();
        // phase 2: thread -> one (row, head-half): 64 contiguous d, 8 half8
        const int m_loc = tid >> 1, nh = tid & 1;
        const int mm = (int)bm + m_loc;
        const int nbase = (int)bn + nh * 64;     // one head exactly
        const int h = (nbase & 1023) >> 6;
        const int bb = mm >> 11, t = mm & 2047;
        size_t db = (((size_t)(bb * HH + h)) * TT + t) * HD;
        _Float16* dst = (seg == 0) ? (q_out + db) : (seg == 1) ? (k_out + db) : (v_out + db);
        const _Float16* src = Sm + m_loc * 132 + nh * 64;  // 8B-aligned only
#pragma unroll
        for (int j = 0; j < 8; j++) {
            half4 lo = *(const half4*)(src + j * 8);
            half4 hi = *(const half4*)(src + j * 8 + 4);
            half8 w;
            w[0] = lo[0]; w[1] = lo[1]; w[2] = lo[2]; w[3] = lo[3];
            w[4] = hi[0]; w[5] = hi[1]; w[6] = hi[2]; w[7] = hi[3];
            *(half8*)(dst + j * 8) = w;
        }
    } else {
        // ---- direct fp32 epilogue (dword stores, 16-lane 64B coalesced)
#pragma unroll
        for (int mt = 0; mt < 4; mt++) {
            int mbase = (int)bm + wr * 64 + mt * 16 + quad * 4;
#pragma unroll
            for (int nt = 0; nt < 4; nt++) {
                int n = (int)bn + wc * 64 + nt * 16 + lc;
                float bv = bias[n];
#pragma unroll
                for (int r = 0; r < 4; r++)
                    c_out[(size_t)(mbase + r) * N + n] = acc[mt][nt][r] + bv;
            }
        }
    }
}

// ---------------------------------------------------------------------------
// Flash attention, S^T formulation, 32 queries/wave (R4 structure).
// Grid (B*H, T/128), 256 thr = 4 waves, q-block 128 -> 4 blocks/CU.
// Key tile = 64. Register prefetch at top of loop (R4 placement).
// ---------------------------------------------------------------------------
__global__ __launch_bounds__(256) void attn_flash(
    const _Float16* __restrict__ Qp, const _Float16* __restrict__ Kp,
    const _Float16* __restrict__ Vp, _Float16* __restrict__ Op)
{
    __shared__ __attribute__((aligned(16))) _Float16 Ks[64][72];  // [key][dim]
    __shared__ __attribute__((aligned(16))) _Float16 Vt[64][76];  // [dim][key]

    const int bh   = blockIdx.x;   // 0..63 (b*16+h)
    const int qt   = blockIdx.y;   // 0..15
    const int tid  = threadIdx.x;
    const int lane = tid & 63;
    const int wave = tid >> 6;     // 0..3
    const int quad = lane >> 4;
    const int lc   = lane & 15;

    const size_t hb = (size_t)bh * TT * HD;
    const _Float16* Kh = Kp + hb;
    const _Float16* Vh = Vp + hb;

    // two query groups per wave; B-frag B[k=dim=quad*8+j][n=q=lc]
    const int q0row = qt * 128 + wave * 32 + lc;
    const int q1row = q0row + 16;
    half8 bq00 = *(const half8*)(Qp + hb + (size_t)q0row * HD + quad * 8);
    half8 bq01 = *(const half8*)(Qp + hb + (size_t)q0row * HD + 32 + quad * 8);
    half8 bq10 = *(const half8*)(Qp + hb + (size_t)q1row * HD + quad * 8);
    half8 bq11 = *(const half8*)(Qp + hb + (size_t)q1row * HD + 32 + quad * 8);

    floatx4 o0[4] = {}, o1[4] = {};  // O^T: dim = dt*16+quad*4+r, q = lc
    float m0 = -1e30f, l0 = 0.f, m1 = -1e30f, l1 = 0.f;

    // staging maps (256 threads)
    const int sk  = tid >> 2;          // K: key 0..63
    const int sc0 = (tid & 3) * 16;    // K: dim chunk base
    const int vkp = tid >> 3;          // V: key pair 0..31
    const int vd8 = (tid & 7) * 8;     // V: dim group 0..56

    const _Float16* Kg  = Kh + (size_t)sk * HD + sc0;
    const _Float16* Vg0 = Vh + (size_t)(2 * vkp) * HD + vd8;
    const _Float16* Vg1 = Vg0 + HD;

    for (int kt = 0; kt < TT; kt += 64) {
        const size_t koff = (size_t)kt * HD;
        half8 kv0 = *(const half8*)(Kg + koff);
        half8 kv1 = *(const half8*)(Kg + koff + 8);
        half8 va  = *(const half8*)(Vg0 + koff);
        half8 vb  = *(const half8*)(Vg1 + koff);
        __syncthreads();  // previous tile fully consumed
        *(half8*)&Ks[sk][sc0]     = kv0;
        *(half8*)&Ks[sk][sc0 + 8] = kv1;
#pragma unroll
        for (int j = 0; j < 8; j++) {
            half2_t w; w[0] = va[j]; w[1] = vb[j];
            *(half2_t*)&Vt[vd8 + j][2 * vkp] = w;
        }
        __syncthreads();  // staging visible

        // ---- S^T = K * Q^T : 4 keytiles x 2 dim-halves x 2 q-groups ----
        floatx4 s0[4], s1[4];
        const floatx4 zf = {0.f, 0.f, 0.f, 0.f};
#pragma unroll
        for (int m = 0; m < 4; m++) {
            half8 a0 = *(const half8*)&Ks[m * 16 + lc][quad * 8];
            half8 a1 = *(const half8*)&Ks[m * 16 + lc][32 + quad * 8];
            s0[m] = __builtin_amdgcn_mfma_f32_16x16x32_f16(a0, bq00, zf, 0, 0, 0);
            s0[m] = __builtin_amdgcn_mfma_f32_16x16x32_f16(a1, bq01, s0[m], 0, 0, 0);
            s1[m] = __builtin_amdgcn_mfma_f32_16x16x32_f16(a0, bq10, zf, 0, 0, 0);
            s1[m] = __builtin_amdgcn_mfma_f32_16x16x32_f16(a1, bq11, s1[m], 0, 0, 0);
        }

        // ---- online softmax per group (exp2; scale folded into Q) ----
        half4 pf0[4], pf1[4];
        {
            float mx = s0[0][0];
#pragma unroll
            for (int m = 0; m < 4; m++)
#pragma unroll
                for (int r = 0; r < 4; r++) mx = fmaxf(mx, s0[m][r]);
            mx = fmaxf(mx, __shfl_xor(mx, 16));
            mx = fmaxf(mx, __shfl_xor(mx, 32));
            float mnew = fmaxf(m0, mx);
            float al = exp2f(m0 - mnew);
            m0 = mnew;
            float rs = 0.f;
#pragma unroll
            for (int m = 0; m < 4; m++) {
                float p0 = exp2f(s0[m][0] - mnew);
                float p1 = exp2f(s0[m][1] - mnew);
                float p2 = exp2f(s0[m][2] - mnew);
                float p3 = exp2f(s0[m][3] - mnew);
                rs += (p0 + p1) + (p2 + p3);
                half4 t;
                t[0] = (_Float16)p0; t[1] = (_Float16)p1;
                t[2] = (_Float16)p2; t[3] = (_Float16)p3;
                pf0[m] = t;
            }
            rs += __shfl_xor(rs, 16);
            rs += __shfl_xor(rs, 32);
            l0 = l0 * al + rs;
#pragma unroll
            for (int dt = 0; dt < 4; dt++) o0[dt] *= al;
        }
        {
            float mx = s1[0][0];
#pragma unroll
            for (int m = 0; m < 4; m++)
#pragma unroll
                for (int r = 0; r < 4; r++) mx = fmaxf(mx, s1[m][r]);
            mx = fmaxf(mx, __shfl_xor(mx, 16));
            mx = fmaxf(mx, __shfl_xor(mx, 32));
            float mnew = fmaxf(m1, mx);
            float al = exp2f(m1 - mnew);
            m1 = mnew;
            float rs = 0.f;
#pragma unroll
            for (int m = 0; m < 4; m++) {
                float p0 = exp2f(s1[m][0] - mnew);
                float p1 = exp2f(s1[m][1] - mnew);
                float p2 = exp2f(s1[m][2] - mnew);
                float p3 = exp2f(s1[m][3] - mnew);
                rs += (p0 + p1) + (p2 + p3);
                half4 t;
                t[0] = (_Float16)p0; t[1] = (_Float16)p1;
                t[2] = (_Float16)p2; t[3] = (_Float16)p3;
                pf1[m] = t;
            }
            rs += __shfl_xor(rs, 16);
            rs += __shfl_xor(rs, 32);
            l1 = l1 * al + rs;
#pragma unroll
            for (int dt = 0; dt < 4; dt++) o1[dt] *= al;
        }

        // ---- O^T += V^T * P^T : V-frags shared across both q-groups ----
#pragma unroll
        for (int dt = 0; dt < 4; dt++) {
            const _Float16* vr = &Vt[dt * 16 + lc][quad * 4];
#pragma unroll
            for (int m = 0; m < 4; m++) {
                half4 vfr = *(const half4*)(vr + m * 16);  // keys m*16+quad*4+{0..3}
                o0[dt] = __builtin_amdgcn_mfma_f32_16x16x16f16(vfr, pf0[m], o0[dt], 0, 0, 0);
                o1[dt] = __builtin_amdgcn_mfma_f32_16x16x16f16(vfr, pf1[m], o1[dt], 0, 0, 0);
            }
        }
    }

    // epilogue: O^T reg (dt, r) -> dim = dt*16 + quad*4 + r, t = q{0,1}row
    const int b = bh >> 4, h = bh & 15;
    {
        float inv = 1.0f / l0;
        size_t base = ((size_t)(b * TT + q0row)) * CC + h * HD;
#pragma unroll
        for (int dt = 0; dt < 4; dt++) {
            half4 hv;
#pragma unroll
            for (int r = 0; r < 4; r++) hv[r] = (_Float16)(o0[dt][r] * inv);
            *(half4*)(Op + base + dt * 16 + quad * 4) = hv;
        }
    }
    {
        float inv = 1.0f / l1;
        size_t base = ((size_t)(b * TT + q1row)) * CC + h * HD;
#pragma unroll
        for (int dt = 0; dt < 4; dt++) {
            half4 hv;
#pragma unroll
            for (int r = 0; r < 4; r++) hv[r] = (_Float16)(o1[dt][r] * inv);
            *(half4*)(Op + base + dt * 16 + quad * 4) = hv;
        }
    }
}

// ---------------------------------------------------------------------------
extern "C" void kernel_launch(void* const* d_in, const int* in_sizes, int n_in,
                              void* d_out, int out_size, void* d_ws, size_t ws_size,
                              hipStream_t stream) {
    const float* x      = (const float*)d_in[0];  // [B,T,C]
    const float* W_attn = (const float*)d_in[1];  // [3C,C]
    const float* b_attn = (const float*)d_in[2];  // [3C]
    const float* W_proj = (const float*)d_in[3];  // [C,C]
    const float* b_proj = (const float*)d_in[4];  // [C]
    float* out = (float*)d_out;

    const size_t SZ_XH  = (size_t)NX * 2;
    const size_t SZ_WA  = (size_t)NWA * 2;
    const size_t SZ_WP  = (size_t)NWP * 2;
    const size_t SZ_QKV = (size_t)BB * HH * TT * HD * 2;
    size_t off = 0;
    _Float16* xh  = (_Float16*)((char*)d_ws + off); off += SZ_XH;
    _Float16* wah = (_Float16*)((char*)d_ws + off); off += SZ_WA;
    _Float16* wph = (_Float16*)((char*)d_ws + off); off += SZ_WP;
    _Float16* Qh  = (_Float16*)((char*)d_ws + off); off += SZ_QKV;
    _Float16* Kh  = (_Float16*)((char*)d_ws + off); off += SZ_QKV;
    _Float16* Vh  = (_Float16*)((char*)d_ws + off); off += SZ_QKV;
    _Float16* Ah  = (_Float16*)((char*)d_ws + off); off += SZ_XH;
    if (ws_size < off) return;

    cvt_all<<<(NX + NWA + NWP) / 8 / 256, 256, 0, stream>>>(
        x, W_attn, W_proj, xh, wah, wph);

    hgemm_nt<0><<<dim3(3 * CC / 128, BB * TT / 128), 256, 0, stream>>>(
        xh, wah, b_attn, Qh, Kh, Vh, nullptr, BB * TT, 3 * CC, CC);

    attn_flash<<<dim3(BB * HH, TT / 128), 256, 0, stream>>>(Qh, Kh, Vh, Ah);

    hgemm_nt<1><<<dim3(CC / 128, BB * TT / 128), 256, 0, stream>>>(
        Ah, wph, b_proj, nullptr, nullptr, nullptr, out, BB * TT, CC, CC);
}